// Round 3
// baseline (176.748 us; speedup 1.0000x reference)
//
#include <hip/hip_runtime.h>

// WaveCell FDTD step, fp32, B=8, NY=NX=1024.
// y = inv*(8*h1 - (4-2b)*h2 + c^2*lap),  b = bg + rho/(1+h1^2),
// c = c_linear + 0.01*rho*h1^2, inv = 1/(4+2b), lap = 5pt zero-pad stencil.
// Outputs concatenated: [y (8M floats), h1 copy (8M floats)].
//
// R5: R4 minus ALL nontemporal hints. Working set = 138 MB inputs + 67 MB
// outputs = 205 MB < 256 MB Infinity Cache. R4's counters showed the nt
// hints forcing a full HBM round-trip every dispatch (WRITE_SIZE = exactly
// the output size; FETCH = half the input) while no other resource was near
// its ceiling. Plain loads/stores let the MALL retain inputs across bench
// iterations and absorb output writes (dirty lines overwritten in-place).
//
// Structure unchanged from R4 (clean A/B): one block = one row, no LDS,
// launch_bounds(256,8), XCD swizzle keeps gy+-1 neighbors + bg slice in the
// owning XCD's L2.

typedef float f4 __attribute__((ext_vector_type(4)));

#define NX4   256      // float4 per row
#define NYDIM 1024

__device__ __forceinline__ float wave_pt(float h1x, float h2x, float clx,
                                         float rx, float bgx, float lap) {
    float s   = h1x * h1x;
    float b   = bgx + rx * __builtin_amdgcn_rcpf(1.0f + s);
    float c   = clx + 0.01f * rx * s;
    float inv = __builtin_amdgcn_rcpf(4.0f + 2.0f * b);
    return inv * (8.0f * h1x - (4.0f - 2.0f * b) * h2x + c * c * lap);
}

__global__ __launch_bounds__(256, 8) void wavecell_kernel(
    const f4* __restrict__ h1,
    const f4* __restrict__ h2,
    const f4* __restrict__ cl,
    const f4* __restrict__ rho,
    const f4* __restrict__ bg,
    f4*       __restrict__ out,
    int n4)   // total float4 groups = B*NY*NX/4 = 2,097,152
{
    const int tid = threadIdx.x;             // f4-column 0..255
    const int bi  = blockIdx.x;              // 0..8191, one block = one row
    const int xcd = bi & 7;
    const int j   = bi >> 3;                 // 0..1023 within XCD
    const int r   = j & 127;                 // row within XCD's slice
    const int bat = j >> 7;                  // batch 0..7
    const int gy  = (xcd << 7) | r;          // image row 0..1023
    const int g   = (bat << 18) + (gy << 8) + tid;   // f4 index

    // h1 center + vertical neighbors (block-uniform edge predicates: no
    // divergence except the 2 edge lanes for L/R).
    const f4 z = {0.f, 0.f, 0.f, 0.f};
    f4 c  = h1[g];
    f4 up = (gy > 0)         ? h1[g - NX4] : z;
    f4 dn = (gy < NYDIM - 1) ? h1[g + NX4] : z;
    const float* h1f = (const float*)h1;
    float L = (tid > 0)       ? h1f[4 * g - 1] : 0.0f;  // prev lane's .w
    float R = (tid < NX4 - 1) ? h1f[4 * g + 4] : 0.0f;  // next lane's .x

    f4 h2c = h2[g];
    f4 clc = cl[g];
    f4 rc  = rho[g];
    f4 bgc = bg[(gy << 8) + tid];            // L2-resident slice

    float lapx = up.x + dn.x + L   + c.y - 4.0f * c.x;
    float lapy = up.y + dn.y + c.x + c.z - 4.0f * c.y;
    float lapz = up.z + dn.z + c.y + c.w - 4.0f * c.z;
    float lapw = up.w + dn.w + c.z + R   - 4.0f * c.w;

    f4 yv;
    yv.x = wave_pt(c.x, h2c.x, clc.x, rc.x, bgc.x, lapx);
    yv.y = wave_pt(c.y, h2c.y, clc.y, rc.y, bgc.y, lapy);
    yv.z = wave_pt(c.z, h2c.z, clc.z, rc.z, bgc.z, lapz);
    yv.w = wave_pt(c.w, h2c.w, clc.w, rc.w, bgc.w, lapw);

    out[g]      = yv;   // output 0: y
    out[n4 + g] = c;    // output 1: h1 copy
}

extern "C" void kernel_launch(void* const* d_in, const int* in_sizes, int n_in,
                              void* d_out, int out_size, void* d_ws, size_t ws_size,
                              hipStream_t stream) {
    const f4* h1  = (const f4*)d_in[0];
    const f4* h2  = (const f4*)d_in[1];
    const f4* cl  = (const f4*)d_in[2];
    const f4* rho = (const f4*)d_in[3];
    const f4* bg  = (const f4*)d_in[4];
    f4* out = (f4*)d_out;

    int n  = in_sizes[0];          // 8*1024*1024
    int n4 = n / 4;                // 2,097,152 float4 groups
    // grid: 8 batches x 1024 rows = 8192 blocks, one row each
    wavecell_kernel<<<8192, 256, 0, stream>>>(h1, h2, cl, rho, bg, out, n4);
}

// Round 4
// 168.564 us; speedup vs baseline: 1.0485x; 1.0485x over previous
//
#include <hip/hip_runtime.h>

// WaveCell FDTD step, fp32, B=8, NY=NX=1024.
// y = inv*(8*h1 - (4-2b)*h2 + c^2*lap),  b = bg + rho/(1+h1^2),
// c = c_linear + 0.01*rho*h1^2, inv = 1/(4+2b), lap = 5pt zero-pad stencil.
// Outputs concatenated: [y (8M floats), h1 copy (8M floats)].
//
// R6: R4's cache policy (nt stores, nt loads for h2/cl/rho, plain h1/bg —
// the best measured: 43 us vs 60 us for plain everything) + 2 rows per
// thread with register-rolled h1. R4/R5 showed HBM bytes are pinned at
// ~133 MB (harness re-poison evicts ~67 MB of MALL-resident input per
// iteration) and BW stalls at 3.2 of 6.3 TB/s with no pipe saturated ->
// outstanding-request-slot bound. This round doubles HBM-path bytes in
// flight per wave (12 f4 loads issued up front) and moves h1 vertical
// reuse from L2 into registers. launch_bounds(256,6): ~80 VGPR fits, 24
// waves/CU >= the 21 R4 actually sustained.
//
// XCD swizzle unchanged: XCD x owns rows [x*128,(x+1)*128) for all batches.

typedef float f4 __attribute__((ext_vector_type(4)));

#define NX4   256      // float4 per row
#define NYDIM 1024

__device__ __forceinline__ float wave_pt(float h1x, float h2x, float clx,
                                         float rx, float bgx, float lap) {
    float s   = h1x * h1x;
    float b   = bgx + rx * __builtin_amdgcn_rcpf(1.0f + s);
    float c   = clx + 0.01f * rx * s;
    float inv = __builtin_amdgcn_rcpf(4.0f + 2.0f * b);
    return inv * (8.0f * h1x - (4.0f - 2.0f * b) * h2x + c * c * lap);
}

__global__ __launch_bounds__(256, 6) void wavecell_kernel(
    const f4* __restrict__ h1,
    const f4* __restrict__ h2,
    const f4* __restrict__ cl,
    const f4* __restrict__ rho,
    const f4* __restrict__ bg,
    f4*       __restrict__ out,
    int n4)   // total float4 groups = B*NY*NX/4 = 2,097,152
{
    const int tid = threadIdx.x;             // f4-column 0..255
    const int bi  = blockIdx.x;              // 0..4095: one block = row pair
    const int xcd = bi & 7;
    const int j   = bi >> 3;                 // 0..511
    const int rpl = j & 63;                  // row-pair within XCD slice
    const int bat = j >> 6;                  // batch 0..7
    const int gy0 = ((xcd << 6) | rpl) << 1; // even row 0..1022
    const int g0  = (bat << 18) + (gy0 << 8) + tid;
    const int g1  = g0 + NX4;

    const f4 z = {0.f, 0.f, 0.f, 0.f};

    // ---- issue ALL global loads up front (max MLP) ----
    // h1 rows gy0-1 .. gy0+2, register-rolled (plain loads: halo reuse via L2)
    f4 rm1 = (gy0 > 0)           ? h1[g0 - NX4] : z;
    f4 c0  = h1[g0];
    f4 c1  = h1[g1];
    f4 r2  = (gy0 < NYDIM - 2)   ? h1[g1 + NX4] : z;

    // horizontal halo: neighbor lanes' cache lines (L1 hits)
    const float* h1f = (const float*)h1;
    float L0 = (tid > 0)       ? h1f[4 * g0 - 1] : 0.0f;
    float R0 = (tid < NX4 - 1) ? h1f[4 * g0 + 4] : 0.0f;
    float L1 = (tid > 0)       ? h1f[4 * g1 - 1] : 0.0f;
    float R1 = (tid < NX4 - 1) ? h1f[4 * g1 + 4] : 0.0f;

    // stream-once arrays: nontemporal
    f4 h2c0 = __builtin_nontemporal_load(h2 + g0);
    f4 h2c1 = __builtin_nontemporal_load(h2 + g1);
    f4 clc0 = __builtin_nontemporal_load(cl + g0);
    f4 clc1 = __builtin_nontemporal_load(cl + g1);
    f4 rc0  = __builtin_nontemporal_load(rho + g0);
    f4 rc1  = __builtin_nontemporal_load(rho + g1);
    f4 bgc0 = bg[(gy0 << 8) + tid];          // L2-resident slice
    f4 bgc1 = bg[((gy0 + 1) << 8) + tid];

    // ---- row 0: up = rm1, dn = c1 ----
    float lapx0 = rm1.x + c1.x + L0   + c0.y - 4.0f * c0.x;
    float lapy0 = rm1.y + c1.y + c0.x + c0.z - 4.0f * c0.y;
    float lapz0 = rm1.z + c1.z + c0.y + c0.w - 4.0f * c0.z;
    float lapw0 = rm1.w + c1.w + c0.z + R0   - 4.0f * c0.w;

    f4 y0;
    y0.x = wave_pt(c0.x, h2c0.x, clc0.x, rc0.x, bgc0.x, lapx0);
    y0.y = wave_pt(c0.y, h2c0.y, clc0.y, rc0.y, bgc0.y, lapy0);
    y0.z = wave_pt(c0.z, h2c0.z, clc0.z, rc0.z, bgc0.z, lapz0);
    y0.w = wave_pt(c0.w, h2c0.w, clc0.w, rc0.w, bgc0.w, lapw0);

    // ---- row 1: up = c0, dn = r2 ----
    float lapx1 = c0.x + r2.x + L1   + c1.y - 4.0f * c1.x;
    float lapy1 = c0.y + r2.y + c1.x + c1.z - 4.0f * c1.y;
    float lapz1 = c0.z + r2.z + c1.y + c1.w - 4.0f * c1.z;
    float lapw1 = c0.w + r2.w + c1.z + R1   - 4.0f * c1.w;

    f4 y1;
    y1.x = wave_pt(c1.x, h2c1.x, clc1.x, rc1.x, bgc1.x, lapx1);
    y1.y = wave_pt(c1.y, h2c1.y, clc1.y, rc1.y, bgc1.y, lapy1);
    y1.z = wave_pt(c1.z, h2c1.z, clc1.z, rc1.z, bgc1.z, lapz1);
    y1.w = wave_pt(c1.w, h2c1.w, clc1.w, rc1.w, bgc1.w, lapw1);

    __builtin_nontemporal_store(y0, out + g0);        // y row 0
    __builtin_nontemporal_store(y1, out + g1);        // y row 1
    __builtin_nontemporal_store(c0, out + n4 + g0);   // h1 copy row 0
    __builtin_nontemporal_store(c1, out + n4 + g1);   // h1 copy row 1
}

extern "C" void kernel_launch(void* const* d_in, const int* in_sizes, int n_in,
                              void* d_out, int out_size, void* d_ws, size_t ws_size,
                              hipStream_t stream) {
    const f4* h1  = (const f4*)d_in[0];
    const f4* h2  = (const f4*)d_in[1];
    const f4* cl  = (const f4*)d_in[2];
    const f4* rho = (const f4*)d_in[3];
    const f4* bg  = (const f4*)d_in[4];
    f4* out = (f4*)d_out;

    int n  = in_sizes[0];          // 8*1024*1024
    int n4 = n / 4;                // 2,097,152 float4 groups
    // grid: 8 batches x 512 row-pairs = 4096 blocks
    wavecell_kernel<<<4096, 256, 0, stream>>>(h1, h2, cl, rho, bg, out, n4);
}